// Round 9
// baseline (914.610 us; speedup 1.0000x reference)
//
#include <hip/hip_runtime.h>
#include <hip/hip_bf16.h>

__device__ __forceinline__ float bf2f(unsigned short u) {
    union { unsigned int i; float f; } c; c.i = ((unsigned int)u) << 16; return c.f;
}
__device__ __forceinline__ unsigned short f2bf(float f) {
    union { unsigned int i; float f; } c; c.f = f;
    unsigned int i = c.i;
    unsigned int r = (i + 0x7FFFu + ((i >> 16) & 1u)) >> 16;
    return (unsigned short)r;
}
__device__ __forceinline__ float u2f_hi(unsigned int u) {
    union { unsigned int i; float f; } c; c.i = u & 0xFFFF0000u; return c.f;
}
__device__ __forceinline__ float u2f_lo(unsigned int u) {
    union { unsigned int i; float f; } c; c.i = u << 16; return c.f;
}
__device__ __forceinline__ int ldi(const void* p, long long i, int is64) {
    return is64 ? (int)((const long long*)p)[i] : ((const int*)p)[i];
}

typedef __attribute__((ext_vector_type(8))) short short8;
typedef __attribute__((ext_vector_type(4))) float floatx4;

#define HID 128
#define EPS 1e-5f

#define OF_WC1 0
#define OF_BC1 128
#define OF_WL1 256
#define OF_BL1 384
#define OF_G1  512
#define OF_BE1 640
#define OF_WC2 768
#define OF_BC2 17152
#define OF_WL2 17280
#define OF_BL2 33664
#define OF_G2  33792
#define OF_BE2 33920
#define OF_W3  34048
#define OF_B3  35328
#define N_CANON 35338

// ---------- detect dtypes from actual bytes ----------
__global__ void k_detect(const unsigned int* __restrict__ g1w,
                         const unsigned int* __restrict__ eiw,
                         int* __restrict__ flags) {
    if (threadIdx.x == 0 && blockIdx.x == 0) {
        flags[0] = (g1w[0] == 0x3F800000u) ? 1 : 0;                        // isf32
        flags[1] = (eiw[1] == 0u && eiw[3] == 0u && eiw[5] == 0u) ? 1 : 0; // is64
    }
}

__global__ void k_zero(int* __restrict__ p, long long n) {
    long long i = (long long)blockIdx.x * blockDim.x + threadIdx.x;
    if (i < n) p[i] = 0;
}

// ---------- convert all weights to canonical fp32 ----------
struct ConvArgs { const void* s[14]; float* d[14]; int n[14]; };
__global__ void k_wconv(ConvArgs a, const int* __restrict__ flags) {
    int seg = blockIdx.y;
    int i = blockIdx.x * 256 + threadIdx.x;
    if (i >= a.n[seg]) return;
    float v = flags[0] ? ((const float*)a.s[seg])[i]
                       : bf2f(((const unsigned short*)a.s[seg])[i]);
    a.d[seg][i] = v;
}

// ---------- W2T[f][k] = bf16( k<128 ? Wc2[k][f] : Wl2[k-128][f] ) ----------
__global__ void k_wT(const float* __restrict__ C, unsigned short* __restrict__ W2T) {
    int i = blockIdx.x * 256 + threadIdx.x;
    if (i >= HID * 256) return;
    int f = i >> 8, k = i & 255;
    float w = (k < HID) ? C[OF_WC2 + k * HID + f] : C[OF_WL2 + (k - HID) * HID + f];
    W2T[f * 256 + k] = f2bf(w);
}

// ---------- in-degree ----------
__global__ void k_deg(const void* __restrict__ ei, int E, int N, const int* __restrict__ flags,
                      int* __restrict__ deg) {
    int i = blockIdx.x * blockDim.x + threadIdx.x;
    if (i < E) {
        int d = ldi(ei, (long long)E + i, flags[1]);
        if ((unsigned)d < (unsigned)N) atomicAdd(&deg[d], 1);
    }
}

// ---------- per-graph node counts via binary search on sorted batch ----------
__global__ void k_cnt2(const void* __restrict__ batch, int N, const int* __restrict__ flags,
                       int* __restrict__ cnt) {
    int g = threadIdx.x;
    int is64 = flags[1];
    auto lb = [&](int t) {
        int lo = 0, hi = N;
        while (lo < hi) { int m = (lo + hi) >> 1; if (ldi(batch, m, is64) < t) lo = m + 1; else hi = m; }
        return lo;
    };
    cnt[g] = lb(g + 1) - lb(g);
}

// ---------- per-node prep: dinv, xf, xd1, rd ----------
__global__ void k_prep(const void* __restrict__ x, const int* __restrict__ deg, int N,
                       const int* __restrict__ flags, float* __restrict__ dinv,
                       float* __restrict__ xf, float* __restrict__ xd1, float* __restrict__ rd) {
    int i = blockIdx.x * blockDim.x + threadIdx.x;
    if (i < N) {
        float dp1 = (float)(max(deg[i], 0) + 1);
        float dv = rsqrtf(dp1);
        float xv = flags[0] ? ((const float*)x)[i] : bf2f(((const unsigned short*)x)[i]);
        dinv[i] = dv;
        xf[i] = xv;
        xd1[i] = xv * dv;
        rd[i] = sqrtf(dp1);
    }
}

// ---------- exclusive scan of deg -> rowptr ----------
__global__ void k_scanA(const int* __restrict__ deg, int N, int* __restrict__ rowptr,
                        int* __restrict__ bsum) {
    __shared__ int sd[256];
    int t = threadIdx.x;
    int i = blockIdx.x * 256 + t;
    int my = (i < N) ? deg[i] : 0;
    sd[t] = my;
    __syncthreads();
    for (int off = 1; off < 256; off <<= 1) {
        int add = (t >= off) ? sd[t - off] : 0;
        __syncthreads();
        sd[t] += add;
        __syncthreads();
    }
    if (i < N) rowptr[i] = sd[t] - my;
    if (t == 255) bsum[blockIdx.x] = sd[255];
}
__global__ void k_scanB(int* __restrict__ bsum, int NB) {
    __shared__ int sd[512];
    int t = threadIdx.x;
    if (NB <= 512) {
        int v = (t < NB) ? bsum[t] : 0;
        sd[t] = v;
        __syncthreads();
        for (int off = 1; off < 512; off <<= 1) {
            int add = (t >= off) ? sd[t - off] : 0;
            __syncthreads();
            sd[t] += add;
            __syncthreads();
        }
        if (t < NB) bsum[t] = sd[t] - v;
    } else if (t == 0) {
        int run = 0;
        for (int b = 0; b < NB; b++) { int v = bsum[b]; bsum[b] = run; run += v; }
    }
}
__global__ void k_scanC(int* __restrict__ rowptr, const int* __restrict__ bsum, int N) {
    int i = blockIdx.x * blockDim.x + threadIdx.x;
    if (i < N) rowptr[i] += bsum[i >> 8];
}

// ---------- CSR fill + fused layer-1 scalar scatter ----------
__global__ void k_fill(const void* __restrict__ ei, int E, int N, const int* __restrict__ flags,
                       const int* __restrict__ rowptr, int* __restrict__ cur,
                       int* __restrict__ col, const float* __restrict__ xd1,
                       float* __restrict__ ps) {
    int i = blockIdx.x * blockDim.x + threadIdx.x;
    if (i < E) {
        int is64 = flags[1];
        int s = ldi(ei, i, is64);
        int d = ldi(ei, (long long)E + i, is64);
        if ((unsigned)s < (unsigned)N && (unsigned)d < (unsigned)N) {
            int idx = rowptr[d] + atomicAdd(&cur[d], 1);
            if ((unsigned)idx < (unsigned)E) col[idx] = s;
            atomicAdd(&ps[d], xd1[s]);
        }
    }
}

// ---------- node scalar pack from ps ----------
__global__ void k_node3(const float* __restrict__ xf, const float* __restrict__ ps,
                        const float* __restrict__ dinv, int N, float4* __restrict__ node) {
    int i = blockIdx.x * blockDim.x + threadIdx.x;
    if (i < N) {
        float dv = dinv[i];
        float xv = xf[i];
        float p = dv * (ps[i] + xv * dv);
        node[i] = make_float4(p, xv, dv, 0.f);
    }
}

// ---------- BN1 stats ----------
#define ROWS1 128
__global__ void k_stats1(const float4* __restrict__ node, const float* __restrict__ C,
                         int N, float* __restrict__ S1, float* __restrict__ S2) {
    int f = threadIdx.x;
    float wc = C[OF_WC1 + f], wl = C[OF_WL1 + f];
    float b = C[OF_BC1 + f] + C[OF_BL1 + f];
    int v0 = blockIdx.x * ROWS1;
    float s1 = 0.f, s2 = 0.f;
    for (int r = 0; r < ROWS1; r++) {
        int v = v0 + r;
        if (v >= N) break;
        float4 nd = node[v];
        float h = fmaxf(nd.x * wc + nd.y * wl + b, 0.f);
        s1 += h; s2 += h * h;
    }
    atomicAdd(&S1[f], s1);
    atomicAdd(&S2[f], s2);
}

// ---------- BN1 affine ----------
__global__ void k_bn1(const float* __restrict__ S1, const float* __restrict__ S2,
                      const float* __restrict__ C, int N, float* __restrict__ ab) {
    int f = threadIdx.x;
    float mu = S1[f] / (float)N;
    float var = S2[f] / (float)N - mu * mu;
    float a = C[OF_G1 + f] * rsqrtf(fmaxf(var, 0.f) + EPS);
    ab[f] = a;
    ab[HID + f] = C[OF_BE1 + f] - mu * a;
}

// ---------- zd[v][f] = dinv[v]*z[v][f], bf16 packed 2/dword ----------
__global__ void k_zmat(const float4* __restrict__ node, const float* __restrict__ C,
                       const float* __restrict__ ab, int N, unsigned int* __restrict__ zd) {
    int i = blockIdx.x * blockDim.x + threadIdx.x;
    if (i >= N * 64) return;
    int v = i >> 6, c = i & 63;
    float4 nd = node[v];
    int f0 = c * 2, f1 = f0 + 1;
    float z0 = ab[f0] * fmaxf(nd.x * C[OF_WC1 + f0] + nd.y * C[OF_WL1 + f0]
                              + C[OF_BC1 + f0] + C[OF_BL1 + f0], 0.f) + ab[HID + f0];
    float z1 = ab[f1] * fmaxf(nd.x * C[OF_WC1 + f1] + nd.y * C[OF_WL1 + f1]
                              + C[OF_BC1 + f1] + C[OF_BL1 + f1], 0.f) + ab[HID + f1];
    float dv = nd.z;
    zd[i] = (unsigned)f2bf(dv * z0) | ((unsigned)f2bf(dv * z1) << 16);
}

// ---------- gather: one wave per dst row, no barriers ----------
__global__ void __launch_bounds__(256) k_gather2(
        const unsigned int* __restrict__ zd, const int* __restrict__ col,
        const int* __restrict__ rowptr, const int* __restrict__ deg,
        const float* __restrict__ dinv, int N, int E, int c0r, int c1r,
        unsigned int* __restrict__ agg) {
    int gt = blockIdx.x * 256 + threadIdx.x;
    int w = gt >> 6, lane = gt & 63;
    int v = c0r + w;
    if (v >= c1r || v >= N) return;
    int base = max(rowptr[v], 0);
    int dn = max(0, min(deg[v], E - base));
    unsigned int us = zd[(size_t)v * 64 + lane];
    float a0 = u2f_lo(us), a1 = u2f_hi(us);
    int j = 0;
    for (; j + 2 <= dn; j += 2) {
        int s0 = col[base + j], s1 = col[base + j + 1];
        if ((unsigned)s0 >= (unsigned)N) s0 = 0;
        if ((unsigned)s1 >= (unsigned)N) s1 = 0;
        unsigned int u0 = zd[(size_t)s0 * 64 + lane];
        unsigned int u1 = zd[(size_t)s1 * 64 + lane];
        a0 += u2f_lo(u0) + u2f_lo(u1);
        a1 += u2f_hi(u0) + u2f_hi(u1);
    }
    if (j < dn) {
        int s = col[base + j];
        if ((unsigned)s >= (unsigned)N) s = 0;
        unsigned int u = zd[(size_t)s * 64 + lane];
        a0 += u2f_lo(u); a1 += u2f_hi(u);
    }
    float dv = dinv[v];
    agg[(size_t)(v - c0r) * 64 + lane] = (unsigned)f2bf(dv * a0) | ((unsigned)f2bf(dv * a1) << 16);
}

// ---------- MFMA GEMM: h2 = [agg z] @ W2T^T + b; LDS-reduced stats/pool epilogue ----------
// A tile: 32 rows x 256 K (bf16, row pad to 264). Two waves: wave w handles rows w*16..w*16+15.
// mfma_f32_16x16x32_bf16: A[m=lane&15][k=quad*8+j]; C/D: col=lane&15, row=quad*4+reg.
#define RG 32
__global__ void __launch_bounds__(128) k_gemm3(
        const unsigned int* __restrict__ zd, const unsigned int* __restrict__ agg,
        const float* __restrict__ rd, const unsigned short* __restrict__ W2T,
        const float* __restrict__ C,
        const void* __restrict__ batch, const int* __restrict__ flags,
        int N, int c0r, int c1r,
        float* __restrict__ S1b, float* __restrict__ S2b, float* __restrict__ G) {
    __shared__ char smem[32 * 264 * 2];          // 16.5 KB; reused as float red[3][8][128]
    unsigned short* azL = (unsigned short*)smem;
    int t = threadIdx.x;
    int vbase = c0r + blockIdx.x * RG;
    int vend = min(c1r, N);
    int is64 = flags[1];
    if (vbase >= vend) return;

    // ---- staging: rows as bf16 [agg(128) | z(128)], row stride 264 ----
    for (int it = 0; it < 16; it++) {
        int idx = it * 128 + t;
        int r = idx >> 6, c = idx & 63;
        int v = vbase + r;
        unsigned ua = 0, uz = 0; float rv = 0.f;
        if (v < vend) {
            ua = agg[(size_t)(v - c0r) * 64 + c];
            uz = zd[(size_t)v * 64 + c];
            rv = rd[v];
        }
        *(unsigned*)&azL[r * 264 + 2 * c] = ua;                 // two agg bf16 as-is
        float z0 = u2f_lo(uz) * rv, z1 = u2f_hi(uz) * rv;
        *(unsigned*)&azL[r * 264 + 128 + 2 * c] =
            (unsigned)f2bf(z0) | ((unsigned)f2bf(z1) << 16);
    }
    __syncthreads();

    int wave = t >> 6, lane = t & 63, quad = lane >> 4, m = lane & 15;

    // ---- A-fragments: register-cached across all col-tiles ----
    short8 afr[8];
#pragma unroll
    for (int kb = 0; kb < 8; kb++)
        afr[kb] = *(const short8*)&azL[(wave * 16 + m) * 264 + kb * 32 + quad * 8];

    int vlast = min(vbase + RG - 1, vend - 1);
    bool uni = (ldi(batch, vbase, is64) == ldi(batch, vlast, is64));

    float ps1[8], ps2[8], pgs[8];
#pragma unroll
    for (int ft = 0; ft < 8; ft++) {
        floatx4 acc = {0.f, 0.f, 0.f, 0.f};
        const unsigned short* brow = &W2T[(ft * 16 + m) * 256];
#pragma unroll
        for (int kb = 0; kb < 8; kb++) {
            short8 bfr = *(const short8*)&brow[kb * 32 + quad * 8];
            acc = __builtin_amdgcn_mfma_f32_16x16x32_bf16(afr[kb], bfr, acc, 0, 0, 0);
        }
        int cgl = ft * 16 + m;
        float bbv = C[OF_BC2 + cgl] + C[OF_BL2 + cgl];
        float s1 = 0.f, s2 = 0.f, gs = 0.f;
#pragma unroll
        for (int reg = 0; reg < 4; reg++) {
            int v = vbase + wave * 16 + quad * 4 + reg;
            if (v < vend) {
                float h = acc[reg] + bbv;
                s1 += h; s2 += h * h;
                if (uni) gs += h;
                else {
                    int g = ldi(batch, v, is64);
                    if ((unsigned)g < 128u) atomicAdd(&G[g * HID + cgl], h);
                }
            }
        }
        ps1[ft] = s1; ps2[ft] = s2; pgs[ft] = gs;
    }

    // ---- LDS reduction: one atomic per feature per block ----
    __syncthreads();
    float* red = (float*)smem;   // [3][8][128]
    int wq = wave * 4 + quad;
#pragma unroll
    for (int ft = 0; ft < 8; ft++) {
        int cgl = ft * 16 + m;
        red[wq * 128 + cgl]        = ps1[ft];
        red[1024 + wq * 128 + cgl] = ps2[ft];
        red[2048 + wq * 128 + cgl] = pgs[ft];
    }
    __syncthreads();
    if (t < HID) {
        float a1 = 0.f, a2 = 0.f, ag = 0.f;
#pragma unroll
        for (int w = 0; w < 8; w++) {
            a1 += red[w * 128 + t];
            a2 += red[1024 + w * 128 + t];
            ag += red[2048 + w * 128 + t];
        }
        atomicAdd(&S1b[t], a1);
        atomicAdd(&S2b[t], a2);
        if (uni) {
            int g = ldi(batch, vbase, is64);
            if ((unsigned)g < 128u) atomicAdd(&G[g * HID + t], ag);
        }
    }
}

// ---------- FALLBACK (round-8 proven): fused gather+GEMM, reduced epilogue ----------
#define R2 32
#define NBUF 128
__global__ void __launch_bounds__(128) k_h2f(
        const float4* __restrict__ node, const int* __restrict__ col,
        const int* __restrict__ rowptr, const int* __restrict__ deg,
        const float* __restrict__ ab, const float* __restrict__ C,
        const void* __restrict__ batch, const int* __restrict__ flags, int N, int E,
        float* __restrict__ S1b, float* __restrict__ S2b, float* __restrict__ G) {
    __shared__ unsigned int azL[R2][HID];
    __shared__ float4 nb[2][NBUF];
    int t = threadIdx.x;
    int v0 = blockIdx.x * R2;
    int is64 = flags[1];
    {
        float wc1 = C[OF_WC1 + t], wl1 = C[OF_WL1 + t];
        float b1 = C[OF_BC1 + t] + C[OF_BL1 + t];
        float a1 = ab[t], be1v = ab[HID + t];
        {
            int v = v0;
            if (v < N) {
                int base = max(rowptr[v], 0);
                int dn = max(0, min(deg[v], E - base));
                int m = min(dn, NBUF);
                if (t < m) {
                    int s = col[base + t];
                    if ((unsigned)s >= (unsigned)N) s = 0;
                    nb[0][t] = node[s];
                }
            }
        }
        for (int r = 0; r < R2; r++) {
            __syncthreads();
            if (r + 1 < R2) {
                int v = v0 + r + 1;
                if (v < N) {
                    int base = max(rowptr[v], 0);
                    int dn = max(0, min(deg[v], E - base));
                    int m = min(dn, NBUF);
                    if (t < m) {
                        int s = col[base + t];
                        if ((unsigned)s >= (unsigned)N) s = 0;
                        nb[(r + 1) & 1][t] = node[s];
                    }
                }
            }
            int v = v0 + r;
            if (v >= N) { azL[r][t] = 0; continue; }
            float4 ndv = node[v];
            float zv = a1 * fmaxf(ndv.x * wc1 + ndv.y * wl1 + b1, 0.f) + be1v;
            float acc = ndv.z * zv;
            int base = max(rowptr[v], 0);
            int dn = max(0, min(deg[v], E - base));
            int m = min(dn, NBUF);
            const float4* buf = nb[r & 1];
            for (int j = 0; j < m; j++) {
                float4 ns = buf[j];
                float zs = a1 * fmaxf(ns.x * wc1 + ns.y * wl1 + b1, 0.f) + be1v;
                acc += ns.z * zs;
            }
            for (int j = NBUF; j < dn; j++) {
                int s = col[base + j];
                if ((unsigned)s >= (unsigned)N) s = 0;
                float4 ns = node[s];
                float zs = a1 * fmaxf(ns.x * wc1 + ns.y * wl1 + b1, 0.f) + be1v;
                acc += ns.z * zs;
            }
            float ag = ndv.z * acc;
            azL[r][t] = ((unsigned)f2bf(ag)) | (((unsigned)f2bf(zv)) << 16);
        }
    }
    __syncthreads();
    int cg = t & 31, rg = t >> 5;
    int c0 = cg * 4, r0 = rg * 8;
    float acc[8][4];
#pragma unroll
    for (int i = 0; i < 8; i++)
#pragma unroll
        for (int j = 0; j < 4; j++) acc[i][j] = 0.f;
    for (int k = 0; k < HID; k += 4) {
        uint4 az[8];
#pragma unroll
        for (int i = 0; i < 8; i++) az[i] = *(const uint4*)&azL[r0 + i][k];
#pragma unroll
        for (int kk = 0; kk < 4; kk++) {
            float4 wc4 = *(const float4*)&C[OF_WC2 + (k + kk) * HID + c0];
            float4 wl4 = *(const float4*)&C[OF_WL2 + (k + kk) * HID + c0];
#pragma unroll
            for (int i = 0; i < 8; i++) {
                unsigned u = ((const unsigned*)&az[i])[kk];
                float A_ = u2f_lo(u);
                float Z_ = u2f_hi(u);
                acc[i][0] += A_ * wc4.x + Z_ * wl4.x;
                acc[i][1] += A_ * wc4.y + Z_ * wl4.y;
                acc[i][2] += A_ * wc4.z + Z_ * wl4.z;
                acc[i][3] += A_ * wc4.w + Z_ * wl4.w;
            }
        }
    }
    float bb[4];
#pragma unroll
    for (int j = 0; j < 4; j++) bb[j] = C[OF_BC2 + c0 + j] + C[OF_BL2 + c0 + j];
    int vlast = min(v0 + R2 - 1, N - 1);
    bool uni = (v0 < N) && (ldi(batch, v0, is64) == ldi(batch, vlast, is64));
    float s1[4] = {0,0,0,0}, s2[4] = {0,0,0,0}, gs[4] = {0,0,0,0};
    for (int i = 0; i < 8; i++) {
        int v = v0 + r0 + i;
        if (v >= N) break;
        float h[4];
#pragma unroll
        for (int j = 0; j < 4; j++) {
            h[j] = acc[i][j] + bb[j];
            s1[j] += h[j];
            s2[j] += h[j] * h[j];
        }
        if (uni) {
#pragma unroll
            for (int j = 0; j < 4; j++) gs[j] += h[j];
        } else {
            int g = ldi(batch, v, is64);
            if ((unsigned)g < 128u) {
#pragma unroll
                for (int j = 0; j < 4; j++) atomicAdd(&G[g * HID + c0 + j], h[j]);
            }
        }
    }
    __syncthreads();
    float* red = (float*)azL;
#pragma unroll
    for (int j = 0; j < 4; j++) {
        red[rg * HID + c0 + j]        = s1[j];
        red[512 + rg * HID + c0 + j]  = s2[j];
        red[1024 + rg * HID + c0 + j] = gs[j];
    }
    __syncthreads();
    if (t < HID) {
        float s1sum = red[t] + red[HID + t] + red[2 * HID + t] + red[3 * HID + t];
        float s2sum = red[512 + t] + red[512 + HID + t] + red[512 + 2 * HID + t] + red[512 + 3 * HID + t];
        atomicAdd(&S1b[t], s1sum);
        atomicAdd(&S2b[t], s2sum);
        if (uni) {
            float gsum = red[1024 + t] + red[1024 + HID + t] + red[1024 + 2 * HID + t] + red[1024 + 3 * HID + t];
            int g = ldi(batch, v0, is64);
            if ((unsigned)g < 128u) atomicAdd(&G[g * HID + t], gsum);
        }
    }
}

// ---------- BN2 affine + mean pool + classifier ----------
__global__ void k_out(const float* __restrict__ G, const int* __restrict__ cnt,
                      const float* __restrict__ S1b, const float* __restrict__ S2b,
                      const float* __restrict__ C, const int* __restrict__ flags,
                      int N, void* __restrict__ out) {
    __shared__ float pb[HID];
    int f = threadIdx.x;
    int g = blockIdx.x;
    float mu = S1b[f] / (float)N;
    float var = S2b[f] / (float)N - mu * mu;
    float a = C[OF_G2 + f] * rsqrtf(fmaxf(var, 0.f) + EPS);
    float be = C[OF_BE2 + f] - mu * a;
    float c = fmaxf((float)cnt[g], 1.f);
    pb[f] = a * (G[g * HID + f] / c) + be;
    __syncthreads();
    if (f < 10) {
        float s = C[OF_B3 + f];
        for (int k = 0; k < HID; k++) s += pb[k] * C[OF_W3 + k * 10 + f];
        if (flags[0]) ((float*)out)[g * 10 + f] = s;
        else ((unsigned short*)out)[g * 10 + f] = f2bf(s);
    }
}

extern "C" void kernel_launch(void* const* d_in, const int* in_sizes, int n_in,
                              void* d_out, int out_size, void* d_ws, size_t ws_size,
                              hipStream_t stream) {
    const void* x   = d_in[0];
    const void* ei  = d_in[1];
    const void* bat = d_in[2];
    const void* w_src[14] = { d_in[3], d_in[4], d_in[5], d_in[6], d_in[7], d_in[8],
                              d_in[9], d_in[10], d_in[11], d_in[12], d_in[13], d_in[14],
                              d_in[15], d_in[16] };
    const int w_cnt[14] = { 128,128,128,128,128,128, 16384,128,16384,128,128,128, 1280,10 };

    const int N = in_sizes[0];
    const int E = in_sizes[1] / 2;
    const int NB = (N + 255) / 256;

    char* ws = (char*)d_ws;
    size_t off = 0;
    auto alloc = [&](size_t bytes) -> void* {
        void* p = ws + off;
        off = (off + bytes + 255) & ~(size_t)255;
        return p;
    };
    // ---- zero-init region (~1.3 MB) ----
    int*   deg  = (int*)  alloc((size_t)N * 4);
    int*   cur  = (int*)  alloc((size_t)N * 4);
    float* ps   = (float*)alloc((size_t)N * 4);
    int*   cnt  = (int*)  alloc(128 * 4);
    float* S1a  = (float*)alloc(HID * 4);
    float* S2a  = (float*)alloc(HID * 4);
    float* S1b  = (float*)alloc(HID * 4);
    float* S2b  = (float*)alloc(HID * 4);
    float* G    = (float*)alloc(128 * HID * 4);
    int*   bsum = (int*)  alloc(2048);
    size_t zbytes = off;
    // ---- fully-overwritten region ----
    int*    flags  = (int*)   alloc(256);
    float*  canon  = (float*) alloc(N_CANON * 4);
    unsigned short* W2T = (unsigned short*)alloc(HID * 256 * 2);
    float*  xf     = (float*) alloc((size_t)N * 4);
    float*  dinv   = (float*) alloc((size_t)N * 4);
    float*  xd1    = (float*) alloc((size_t)N * 4);
    float*  rd     = (float*) alloc((size_t)N * 4);
    float4* node   = (float4*)alloc((size_t)N * 16);
    int*    rowptr = (int*)   alloc((size_t)N * 4);
    int*    col    = (int*)   alloc((size_t)E * 4);
    float*  ab     = (float*) alloc(2 * HID * 4);
    // ---- fast-path buffers (zd + chunked agg), guarded by ws_size ----
    unsigned int* zd = (unsigned int*)alloc((size_t)N * 256);
    size_t availAgg = (ws_size > off) ? (ws_size - off) : 0;
    bool fast = (ws_size >= off) && (availAgg >= (2u << 20));
    unsigned int* agg = (unsigned int*)(ws + off);
    int rowsPer = N, nchunk = 1;
    if (fast) {
        size_t need = (size_t)N * 256;
        if (availAgg < need) {
            rowsPer = (int)(availAgg / 256) & ~31;
            if (rowsPer < 32) fast = false;
            else nchunk = (N + rowsPer - 1) / rowsPer;
        }
    }
    (void)n_in; (void)out_size;

    ConvArgs ca;
    int w_off[14] = { OF_WC1, OF_BC1, OF_WL1, OF_BL1, OF_G1, OF_BE1,
                      OF_WC2, OF_BC2, OF_WL2, OF_BL2, OF_G2, OF_BE2, OF_W3, OF_B3 };
    for (int i = 0; i < 14; i++) { ca.s[i] = w_src[i]; ca.d[i] = canon + w_off[i]; ca.n[i] = w_cnt[i]; }

    const int tb = 256;
    long long zn = (long long)(zbytes / 4);
    k_detect<<<1, 64, 0, stream>>>((const unsigned int*)d_in[7], (const unsigned int*)ei, flags);
    k_zero  <<<(int)((zn + tb - 1) / tb), tb, 0, stream>>>((int*)d_ws, zn);
    k_wconv <<<dim3(64, 14), 256, 0, stream>>>(ca, flags);
    k_wT    <<<(HID * 256 + tb - 1) / tb, tb, 0, stream>>>(canon, W2T);
    k_deg   <<<(E + tb - 1) / tb, tb, 0, stream>>>(ei, E, N, flags, deg);
    k_cnt2  <<<1, 128, 0, stream>>>(bat, N, flags, cnt);
    k_prep  <<<(N + tb - 1) / tb, tb, 0, stream>>>(x, deg, N, flags, dinv, xf, xd1, rd);
    k_scanA <<<NB, 256, 0, stream>>>(deg, N, rowptr, bsum);
    k_scanB <<<1, 512, 0, stream>>>(bsum, NB);
    k_scanC <<<NB, 256, 0, stream>>>(rowptr, bsum, N);
    k_fill  <<<(E + tb - 1) / tb, tb, 0, stream>>>(ei, E, N, flags, rowptr, cur, col, xd1, ps);
    k_node3 <<<(N + tb - 1) / tb, tb, 0, stream>>>(xf, ps, dinv, N, node);
    k_stats1<<<(N + ROWS1 - 1) / ROWS1, HID, 0, stream>>>(node, canon, N, S1a, S2a);
    k_bn1   <<<1, HID, 0, stream>>>(S1a, S2a, canon, N, ab);
    if (fast) {
        k_zmat<<<(N * 64 + tb - 1) / tb, tb, 0, stream>>>(node, canon, ab, N, zd);
        for (int c = 0; c < nchunk; c++) {
            int c0r = c * rowsPer;
            int c1r = min(N, c0r + rowsPer);
            int rows = c1r - c0r;
            k_gather2<<<(rows * 64 + tb - 1) / tb, tb, 0, stream>>>(zd, col, rowptr, deg, dinv,
                                                                    N, E, c0r, c1r, agg);
            k_gemm3<<<(rows + RG - 1) / RG, 128, 0, stream>>>(zd, agg, rd, W2T, canon, bat, flags,
                                                              N, c0r, c1r, S1b, S2b, G);
        }
    } else {
        k_h2f<<<(N + R2 - 1) / R2, HID, 0, stream>>>(node, col, rowptr, deg, ab, canon,
                                                     bat, flags, N, E, S1b, S2b, G);
    }
    k_out<<<128, HID, 0, stream>>>(G, cnt, S1b, S2b, canon, flags, N, d_out);
}

// Round 10
// 739.548 us; speedup vs baseline: 1.2367x; 1.2367x over previous
//
#include <hip/hip_runtime.h>
#include <hip/hip_bf16.h>

__device__ __forceinline__ float bf2f(unsigned short u) {
    union { unsigned int i; float f; } c; c.i = ((unsigned int)u) << 16; return c.f;
}
__device__ __forceinline__ unsigned short f2bf(float f) {
    union { unsigned int i; float f; } c; c.f = f;
    unsigned int i = c.i;
    unsigned int r = (i + 0x7FFFu + ((i >> 16) & 1u)) >> 16;
    return (unsigned short)r;
}
__device__ __forceinline__ float u2f_hi(unsigned int u) {
    union { unsigned int i; float f; } c; c.i = u & 0xFFFF0000u; return c.f;
}
__device__ __forceinline__ float u2f_lo(unsigned int u) {
    union { unsigned int i; float f; } c; c.i = u << 16; return c.f;
}
__device__ __forceinline__ int ldi(const void* p, long long i, int is64) {
    return is64 ? (int)((const long long*)p)[i] : ((const int*)p)[i];
}

typedef __attribute__((ext_vector_type(8))) short short8;
typedef __attribute__((ext_vector_type(4))) float floatx4;

#define HID 128
#define EPS 1e-5f

#define OF_WC1 0
#define OF_BC1 128
#define OF_WL1 256
#define OF_BL1 384
#define OF_G1  512
#define OF_BE1 640
#define OF_WC2 768
#define OF_BC2 17152
#define OF_WL2 17280
#define OF_BL2 33664
#define OF_G2  33792
#define OF_BE2 33920
#define OF_W3  34048
#define OF_B3  35328
#define N_CANON 35338

// ---------- detect dtypes from actual bytes ----------
__global__ void k_detect(const unsigned int* __restrict__ g1w,
                         const unsigned int* __restrict__ eiw,
                         int* __restrict__ flags) {
    if (threadIdx.x == 0 && blockIdx.x == 0) {
        flags[0] = (g1w[0] == 0x3F800000u) ? 1 : 0;                        // isf32
        flags[1] = (eiw[1] == 0u && eiw[3] == 0u && eiw[5] == 0u) ? 1 : 0; // is64
    }
}

__global__ void k_zero(int* __restrict__ p, long long n) {
    long long i = (long long)blockIdx.x * blockDim.x + threadIdx.x;
    if (i < n) p[i] = 0;
}

// ---------- convert all weights to canonical fp32 ----------
struct ConvArgs { const void* s[14]; float* d[14]; int n[14]; };
__global__ void k_wconv(ConvArgs a, const int* __restrict__ flags) {
    int seg = blockIdx.y;
    int i = blockIdx.x * 256 + threadIdx.x;
    if (i >= a.n[seg]) return;
    float v = flags[0] ? ((const float*)a.s[seg])[i]
                       : bf2f(((const unsigned short*)a.s[seg])[i]);
    a.d[seg][i] = v;
}

// ---------- W2T[f][k] = bf16( k<128 ? Wc2[k][f] : Wl2[k-128][f] ) ----------
__global__ void k_wT(const float* __restrict__ C, unsigned short* __restrict__ W2T) {
    int i = blockIdx.x * 256 + threadIdx.x;
    if (i >= HID * 256) return;
    int f = i >> 8, k = i & 255;
    float w = (k < HID) ? C[OF_WC2 + k * HID + f] : C[OF_WL2 + (k - HID) * HID + f];
    W2T[f * 256 + k] = f2bf(w);
}

// ---------- in-degree + per-edge slot (atomic return) ----------
__global__ void k_deg(const void* __restrict__ ei, int E, int N, const int* __restrict__ flags,
                      int* __restrict__ deg, int* __restrict__ slot) {
    int i = blockIdx.x * blockDim.x + threadIdx.x;
    if (i < E) {
        int d = ldi(ei, (long long)E + i, flags[1]);
        int sl = 0;
        if ((unsigned)d < (unsigned)N) sl = atomicAdd(&deg[d], 1);
        slot[i] = sl;
    }
}

// ---------- per-graph node counts via binary search on sorted batch ----------
__global__ void k_cnt2(const void* __restrict__ batch, int N, const int* __restrict__ flags,
                       int* __restrict__ cnt) {
    int g = threadIdx.x;
    int is64 = flags[1];
    auto lb = [&](int t) {
        int lo = 0, hi = N;
        while (lo < hi) { int m = (lo + hi) >> 1; if (ldi(batch, m, is64) < t) lo = m + 1; else hi = m; }
        return lo;
    };
    cnt[g] = lb(g + 1) - lb(g);
}

// ---------- per-node prep: dinv, xf, xd1, rd ----------
__global__ void k_prep(const void* __restrict__ x, const int* __restrict__ deg, int N,
                       const int* __restrict__ flags, float* __restrict__ dinv,
                       float* __restrict__ xf, float* __restrict__ xd1, float* __restrict__ rd) {
    int i = blockIdx.x * blockDim.x + threadIdx.x;
    if (i < N) {
        float dp1 = (float)(max(deg[i], 0) + 1);
        float dv = rsqrtf(dp1);
        float xv = flags[0] ? ((const float*)x)[i] : bf2f(((const unsigned short*)x)[i]);
        dinv[i] = dv;
        xf[i] = xv;
        xd1[i] = xv * dv;
        rd[i] = sqrtf(dp1);
    }
}

// ---------- exclusive scan of deg -> rowptr ----------
__global__ void k_scanA(const int* __restrict__ deg, int N, int* __restrict__ rowptr,
                        int* __restrict__ bsum) {
    __shared__ int sd[256];
    int t = threadIdx.x;
    int i = blockIdx.x * 256 + t;
    int my = (i < N) ? deg[i] : 0;
    sd[t] = my;
    __syncthreads();
    for (int off = 1; off < 256; off <<= 1) {
        int add = (t >= off) ? sd[t - off] : 0;
        __syncthreads();
        sd[t] += add;
        __syncthreads();
    }
    if (i < N) rowptr[i] = sd[t] - my;
    if (t == 255) bsum[blockIdx.x] = sd[255];
}
__global__ void k_scanB(int* __restrict__ bsum, int NB) {
    __shared__ int sd[512];
    int t = threadIdx.x;
    if (NB <= 512) {
        int v = (t < NB) ? bsum[t] : 0;
        sd[t] = v;
        __syncthreads();
        for (int off = 1; off < 512; off <<= 1) {
            int add = (t >= off) ? sd[t - off] : 0;
            __syncthreads();
            sd[t] += add;
            __syncthreads();
        }
        if (t < NB) bsum[t] = sd[t] - v;
    } else if (t == 0) {
        int run = 0;
        for (int b = 0; b < NB; b++) { int v = bsum[b]; bsum[b] = run; run += v; }
    }
}
__global__ void k_scanC(int* __restrict__ rowptr, const int* __restrict__ bsum, int N) {
    int i = blockIdx.x * blockDim.x + threadIdx.x;
    if (i < N) rowptr[i] += bsum[i >> 8];
}

// ---------- CSR fill (atomic-free placement via slot) + layer-1 scalar scatter ----------
__global__ void k_fill(const void* __restrict__ ei, int E, int N, const int* __restrict__ flags,
                       const int* __restrict__ rowptr, const int* __restrict__ slot,
                       int* __restrict__ col, const float* __restrict__ xd1,
                       float* __restrict__ ps) {
    int i = blockIdx.x * blockDim.x + threadIdx.x;
    if (i < E) {
        int is64 = flags[1];
        int s = ldi(ei, i, is64);
        int d = ldi(ei, (long long)E + i, is64);
        if ((unsigned)s < (unsigned)N && (unsigned)d < (unsigned)N) {
            int idx = rowptr[d] + slot[i];
            if ((unsigned)idx < (unsigned)E) col[idx] = s;
            atomicAdd(&ps[d], xd1[s]);
        }
    }
}

// ---------- node scalar pack from ps ----------
__global__ void k_node3(const float* __restrict__ xf, const float* __restrict__ ps,
                        const float* __restrict__ dinv, int N, float4* __restrict__ node) {
    int i = blockIdx.x * blockDim.x + threadIdx.x;
    if (i < N) {
        float dv = dinv[i];
        float xv = xf[i];
        float p = dv * (ps[i] + xv * dv);
        node[i] = make_float4(p, xv, dv, 0.f);
    }
}

// ---------- BN1 stats ----------
#define ROWS1 128
__global__ void k_stats1(const float4* __restrict__ node, const float* __restrict__ C,
                         int N, float* __restrict__ S1, float* __restrict__ S2) {
    int f = threadIdx.x;
    float wc = C[OF_WC1 + f], wl = C[OF_WL1 + f];
    float b = C[OF_BC1 + f] + C[OF_BL1 + f];
    int v0 = blockIdx.x * ROWS1;
    float s1 = 0.f, s2 = 0.f;
    for (int r = 0; r < ROWS1; r++) {
        int v = v0 + r;
        if (v >= N) break;
        float4 nd = node[v];
        float h = fmaxf(nd.x * wc + nd.y * wl + b, 0.f);
        s1 += h; s2 += h * h;
    }
    atomicAdd(&S1[f], s1);
    atomicAdd(&S2[f], s2);
}

// ---------- BN1 affine ----------
__global__ void k_bn1(const float* __restrict__ S1, const float* __restrict__ S2,
                      const float* __restrict__ C, int N, float* __restrict__ ab) {
    int f = threadIdx.x;
    float mu = S1[f] / (float)N;
    float var = S2[f] / (float)N - mu * mu;
    float a = C[OF_G1 + f] * rsqrtf(fmaxf(var, 0.f) + EPS);
    ab[f] = a;
    ab[HID + f] = C[OF_BE1 + f] - mu * a;
}

// ---------- zd[v][f] = dinv[v]*z[v][f], bf16 packed 2/dword ----------
__global__ void k_zmat(const float4* __restrict__ node, const float* __restrict__ C,
                       const float* __restrict__ ab, int N, unsigned int* __restrict__ zd) {
    int i = blockIdx.x * blockDim.x + threadIdx.x;
    if (i >= N * 64) return;
    int v = i >> 6, c = i & 63;
    float4 nd = node[v];
    int f0 = c * 2, f1 = f0 + 1;
    float z0 = ab[f0] * fmaxf(nd.x * C[OF_WC1 + f0] + nd.y * C[OF_WL1 + f0]
                              + C[OF_BC1 + f0] + C[OF_BL1 + f0], 0.f) + ab[HID + f0];
    float z1 = ab[f1] * fmaxf(nd.x * C[OF_WC1 + f1] + nd.y * C[OF_WL1 + f1]
                              + C[OF_BC1 + f1] + C[OF_BL1 + f1], 0.f) + ab[HID + f1];
    float dv = nd.z;
    zd[i] = (unsigned)f2bf(dv * z0) | ((unsigned)f2bf(dv * z1) << 16);
}

// ---------- gather: one wave per dst row; scalar col loads, 4-wide body ----------
__global__ void __launch_bounds__(256) k_gather2(
        const unsigned int* __restrict__ zd, const int* __restrict__ col,
        const int* __restrict__ rowptr, const int* __restrict__ deg,
        const float* __restrict__ dinv, int N, int E, int c0r, int c1r,
        unsigned int* __restrict__ agg) {
    int gt = blockIdx.x * 256 + threadIdx.x;
    int w = gt >> 6, lane = gt & 63;
    int v = c0r + w;
    if (v >= c1r || v >= N) return;
    int base = max(rowptr[v], 0);
    int dn = max(0, min(deg[v], E - base));
    base = __builtin_amdgcn_readfirstlane(base);
    dn = __builtin_amdgcn_readfirstlane(dn);
    unsigned int us = zd[(size_t)v * 64 + lane];
    float a0 = u2f_lo(us), a1 = u2f_hi(us);
    int j = 0;
    int head = min(dn, (4 - (base & 3)) & 3);
    for (; j < head; j++) {
        int s = col[base + j];
        if ((unsigned)s >= (unsigned)N) s = 0;
        unsigned int u = zd[(size_t)s * 64 + lane];
        a0 += u2f_lo(u); a1 += u2f_hi(u);
    }
    for (; j + 4 <= dn; j += 4) {
        int4 cc = *(const int4*)&col[base + j];   // 16B-aligned scalar load
        int s0 = cc.x, s1 = cc.y, s2 = cc.z, s3 = cc.w;
        if ((unsigned)s0 >= (unsigned)N) s0 = 0;
        if ((unsigned)s1 >= (unsigned)N) s1 = 0;
        if ((unsigned)s2 >= (unsigned)N) s2 = 0;
        if ((unsigned)s3 >= (unsigned)N) s3 = 0;
        unsigned int u0 = zd[(size_t)s0 * 64 + lane];
        unsigned int u1 = zd[(size_t)s1 * 64 + lane];
        unsigned int u2 = zd[(size_t)s2 * 64 + lane];
        unsigned int u3 = zd[(size_t)s3 * 64 + lane];
        a0 += u2f_lo(u0) + u2f_lo(u1) + u2f_lo(u2) + u2f_lo(u3);
        a1 += u2f_hi(u0) + u2f_hi(u1) + u2f_hi(u2) + u2f_hi(u3);
    }
    for (; j < dn; j++) {
        int s = col[base + j];
        if ((unsigned)s >= (unsigned)N) s = 0;
        unsigned int u = zd[(size_t)s * 64 + lane];
        a0 += u2f_lo(u); a1 += u2f_hi(u);
    }
    float dv = dinv[v];
    agg[(size_t)(v - c0r) * 64 + lane] = (unsigned)f2bf(dv * a0) | ((unsigned)f2bf(dv * a1) << 16);
}

// ---------- MFMA GEMM: h2 = [agg z] @ W2T^T + b; LDS-reduced stats/pool epilogue ----------
#define RG 32
__global__ void __launch_bounds__(128) k_gemm3(
        const unsigned int* __restrict__ zd, const unsigned int* __restrict__ agg,
        const float* __restrict__ rd, const unsigned short* __restrict__ W2T,
        const float* __restrict__ C,
        const void* __restrict__ batch, const int* __restrict__ flags,
        int N, int c0r, int c1r,
        float* __restrict__ S1b, float* __restrict__ S2b, float* __restrict__ G) {
    __shared__ char smem[32 * 264 * 2];          // 16.5 KB; reused as float red[3][8][128]
    unsigned short* azL = (unsigned short*)smem;
    int t = threadIdx.x;
    int vbase = c0r + blockIdx.x * RG;
    int vend = min(c1r, N);
    int is64 = flags[1];
    if (vbase >= vend) return;

    for (int it = 0; it < 16; it++) {
        int idx = it * 128 + t;
        int r = idx >> 6, c = idx & 63;
        int v = vbase + r;
        unsigned ua = 0, uz = 0; float rv = 0.f;
        if (v < vend) {
            ua = agg[(size_t)(v - c0r) * 64 + c];
            uz = zd[(size_t)v * 64 + c];
            rv = rd[v];
        }
        *(unsigned*)&azL[r * 264 + 2 * c] = ua;
        float z0 = u2f_lo(uz) * rv, z1 = u2f_hi(uz) * rv;
        *(unsigned*)&azL[r * 264 + 128 + 2 * c] =
            (unsigned)f2bf(z0) | ((unsigned)f2bf(z1) << 16);
    }
    __syncthreads();

    int wave = t >> 6, lane = t & 63, quad = lane >> 4, m = lane & 15;

    short8 afr[8];
#pragma unroll
    for (int kb = 0; kb < 8; kb++)
        afr[kb] = *(const short8*)&azL[(wave * 16 + m) * 264 + kb * 32 + quad * 8];

    int vlast = min(vbase + RG - 1, vend - 1);
    bool uni = (ldi(batch, vbase, is64) == ldi(batch, vlast, is64));

    float ps1[8], ps2[8], pgs[8];
#pragma unroll
    for (int ft = 0; ft < 8; ft++) {
        floatx4 acc = {0.f, 0.f, 0.f, 0.f};
        const unsigned short* brow = &W2T[(ft * 16 + m) * 256];
#pragma unroll
        for (int kb = 0; kb < 8; kb++) {
            short8 bfr = *(const short8*)&brow[kb * 32 + quad * 8];
            acc = __builtin_amdgcn_mfma_f32_16x16x32_bf16(afr[kb], bfr, acc, 0, 0, 0);
        }
        int cgl = ft * 16 + m;
        float bbv = C[OF_BC2 + cgl] + C[OF_BL2 + cgl];
        float s1 = 0.f, s2 = 0.f, gs = 0.f;
#pragma unroll
        for (int reg = 0; reg < 4; reg++) {
            int v = vbase + wave * 16 + quad * 4 + reg;
            if (v < vend) {
                float h = acc[reg] + bbv;
                s1 += h; s2 += h * h;
                if (uni) gs += h;
                else {
                    int g = ldi(batch, v, is64);
                    if ((unsigned)g < 128u) atomicAdd(&G[g * HID + cgl], h);
                }
            }
        }
        ps1[ft] = s1; ps2[ft] = s2; pgs[ft] = gs;
    }

    __syncthreads();
    float* red = (float*)smem;
    int wq = wave * 4 + quad;
#pragma unroll
    for (int ft = 0; ft < 8; ft++) {
        int cgl = ft * 16 + m;
        red[wq * 128 + cgl]        = ps1[ft];
        red[1024 + wq * 128 + cgl] = ps2[ft];
        red[2048 + wq * 128 + cgl] = pgs[ft];
    }
    __syncthreads();
    if (t < HID) {
        float a1 = 0.f, a2 = 0.f, ag = 0.f;
#pragma unroll
        for (int w = 0; w < 8; w++) {
            a1 += red[w * 128 + t];
            a2 += red[1024 + w * 128 + t];
            ag += red[2048 + w * 128 + t];
        }
        atomicAdd(&S1b[t], a1);
        atomicAdd(&S2b[t], a2);
        if (uni) {
            int g = ldi(batch, vbase, is64);
            if ((unsigned)g < 128u) atomicAdd(&G[g * HID + t], ag);
        }
    }
}

// ---------- FALLBACK (round-8 proven): fused gather+GEMM, reduced epilogue ----------
#define R2 32
#define NBUF 128
__global__ void __launch_bounds__(128) k_h2f(
        const float4* __restrict__ node, const int* __restrict__ col,
        const int* __restrict__ rowptr, const int* __restrict__ deg,
        const float* __restrict__ ab, const float* __restrict__ C,
        const void* __restrict__ batch, const int* __restrict__ flags, int N, int E,
        float* __restrict__ S1b, float* __restrict__ S2b, float* __restrict__ G) {
    __shared__ unsigned int azL[R2][HID];
    __shared__ float4 nb[2][NBUF];
    int t = threadIdx.x;
    int v0 = blockIdx.x * R2;
    int is64 = flags[1];
    {
        float wc1 = C[OF_WC1 + t], wl1 = C[OF_WL1 + t];
        float b1 = C[OF_BC1 + t] + C[OF_BL1 + t];
        float a1 = ab[t], be1v = ab[HID + t];
        {
            int v = v0;
            if (v < N) {
                int base = max(rowptr[v], 0);
                int dn = max(0, min(deg[v], E - base));
                int m = min(dn, NBUF);
                if (t < m) {
                    int s = col[base + t];
                    if ((unsigned)s >= (unsigned)N) s = 0;
                    nb[0][t] = node[s];
                }
            }
        }
        for (int r = 0; r < R2; r++) {
            __syncthreads();
            if (r + 1 < R2) {
                int v = v0 + r + 1;
                if (v < N) {
                    int base = max(rowptr[v], 0);
                    int dn = max(0, min(deg[v], E - base));
                    int m = min(dn, NBUF);
                    if (t < m) {
                        int s = col[base + t];
                        if ((unsigned)s >= (unsigned)N) s = 0;
                        nb[(r + 1) & 1][t] = node[s];
                    }
                }
            }
            int v = v0 + r;
            if (v >= N) { azL[r][t] = 0; continue; }
            float4 ndv = node[v];
            float zv = a1 * fmaxf(ndv.x * wc1 + ndv.y * wl1 + b1, 0.f) + be1v;
            float acc = ndv.z * zv;
            int base = max(rowptr[v], 0);
            int dn = max(0, min(deg[v], E - base));
            int m = min(dn, NBUF);
            const float4* buf = nb[r & 1];
            for (int j = 0; j < m; j++) {
                float4 ns = buf[j];
                float zs = a1 * fmaxf(ns.x * wc1 + ns.y * wl1 + b1, 0.f) + be1v;
                acc += ns.z * zs;
            }
            for (int j = NBUF; j < dn; j++) {
                int s = col[base + j];
                if ((unsigned)s >= (unsigned)N) s = 0;
                float4 ns = node[s];
                float zs = a1 * fmaxf(ns.x * wc1 + ns.y * wl1 + b1, 0.f) + be1v;
                acc += ns.z * zs;
            }
            float ag = ndv.z * acc;
            azL[r][t] = ((unsigned)f2bf(ag)) | (((unsigned)f2bf(zv)) << 16);
        }
    }
    __syncthreads();
    int cg = t & 31, rg = t >> 5;
    int c0 = cg * 4, r0 = rg * 8;
    float acc[8][4];
#pragma unroll
    for (int i = 0; i < 8; i++)
#pragma unroll
        for (int j = 0; j < 4; j++) acc[i][j] = 0.f;
    for (int k = 0; k < HID; k += 4) {
        uint4 az[8];
#pragma unroll
        for (int i = 0; i < 8; i++) az[i] = *(const uint4*)&azL[r0 + i][k];
#pragma unroll
        for (int kk = 0; kk < 4; kk++) {
            float4 wc4 = *(const float4*)&C[OF_WC2 + (k + kk) * HID + c0];
            float4 wl4 = *(const float4*)&C[OF_WL2 + (k + kk) * HID + c0];
#pragma unroll
            for (int i = 0; i < 8; i++) {
                unsigned u = ((const unsigned*)&az[i])[kk];
                float A_ = u2f_lo(u);
                float Z_ = u2f_hi(u);
                acc[i][0] += A_ * wc4.x + Z_ * wl4.x;
                acc[i][1] += A_ * wc4.y + Z_ * wl4.y;
                acc[i][2] += A_ * wc4.z + Z_ * wl4.z;
                acc[i][3] += A_ * wc4.w + Z_ * wl4.w;
            }
        }
    }
    float bb[4];
#pragma unroll
    for (int j = 0; j < 4; j++) bb[j] = C[OF_BC2 + c0 + j] + C[OF_BL2 + c0 + j];
    int vlast = min(v0 + R2 - 1, N - 1);
    bool uni = (v0 < N) && (ldi(batch, v0, is64) == ldi(batch, vlast, is64));
    float s1[4] = {0,0,0,0}, s2[4] = {0,0,0,0}, gs[4] = {0,0,0,0};
    for (int i = 0; i < 8; i++) {
        int v = v0 + r0 + i;
        if (v >= N) break;
        float h[4];
#pragma unroll
        for (int j = 0; j < 4; j++) {
            h[j] = acc[i][j] + bb[j];
            s1[j] += h[j];
            s2[j] += h[j] * h[j];
        }
        if (uni) {
#pragma unroll
            for (int j = 0; j < 4; j++) gs[j] += h[j];
        } else {
            int g = ldi(batch, v, is64);
            if ((unsigned)g < 128u) {
#pragma unroll
                for (int j = 0; j < 4; j++) atomicAdd(&G[g * HID + c0 + j], h[j]);
            }
        }
    }
    __syncthreads();
    float* red = (float*)azL;
#pragma unroll
    for (int j = 0; j < 4; j++) {
        red[rg * HID + c0 + j]        = s1[j];
        red[512 + rg * HID + c0 + j]  = s2[j];
        red[1024 + rg * HID + c0 + j] = gs[j];
    }
    __syncthreads();
    if (t < HID) {
        float s1sum = red[t] + red[HID + t] + red[2 * HID + t] + red[3 * HID + t];
        float s2sum = red[512 + t] + red[512 + HID + t] + red[512 + 2 * HID + t] + red[512 + 3 * HID + t];
        atomicAdd(&S1b[t], s1sum);
        atomicAdd(&S2b[t], s2sum);
        if (uni) {
            float gsum = red[1024 + t] + red[1024 + HID + t] + red[1024 + 2 * HID + t] + red[1024 + 3 * HID + t];
            int g = ldi(batch, v0, is64);
            if ((unsigned)g < 128u) atomicAdd(&G[g * HID + t], gsum);
        }
    }
}

// ---------- BN2 affine + mean pool + classifier ----------
__global__ void k_out(const float* __restrict__ G, const int* __restrict__ cnt,
                      const float* __restrict__ S1b, const float* __restrict__ S2b,
                      const float* __restrict__ C, const int* __restrict__ flags,
                      int N, void* __restrict__ out) {
    __shared__ float pb[HID];
    int f = threadIdx.x;
    int g = blockIdx.x;
    float mu = S1b[f] / (float)N;
    float var = S2b[f] / (float)N - mu * mu;
    float a = C[OF_G2 + f] * rsqrtf(fmaxf(var, 0.f) + EPS);
    float be = C[OF_BE2 + f] - mu * a;
    float c = fmaxf((float)cnt[g], 1.f);
    pb[f] = a * (G[g * HID + f] / c) + be;
    __syncthreads();
    if (f < 10) {
        float s = C[OF_B3 + f];
        for (int k = 0; k < HID; k++) s += pb[k] * C[OF_W3 + k * 10 + f];
        if (flags[0]) ((float*)out)[g * 10 + f] = s;
        else ((unsigned short*)out)[g * 10 + f] = f2bf(s);
    }
}

extern "C" void kernel_launch(void* const* d_in, const int* in_sizes, int n_in,
                              void* d_out, int out_size, void* d_ws, size_t ws_size,
                              hipStream_t stream) {
    const void* x   = d_in[0];
    const void* ei  = d_in[1];
    const void* bat = d_in[2];
    const void* w_src[14] = { d_in[3], d_in[4], d_in[5], d_in[6], d_in[7], d_in[8],
                              d_in[9], d_in[10], d_in[11], d_in[12], d_in[13], d_in[14],
                              d_in[15], d_in[16] };
    const int w_cnt[14] = { 128,128,128,128,128,128, 16384,128,16384,128,128,128, 1280,10 };

    const int N = in_sizes[0];
    const int E = in_sizes[1] / 2;
    const int NB = (N + 255) / 256;

    char* ws = (char*)d_ws;
    size_t off = 0;
    auto alloc = [&](size_t bytes) -> void* {
        void* p = ws + off;
        off = (off + bytes + 255) & ~(size_t)255;
        return p;
    };
    // ---- zero-init region (~0.9 MB) ----
    int*   deg  = (int*)  alloc((size_t)N * 4);
    float* ps   = (float*)alloc((size_t)N * 4);
    int*   cnt  = (int*)  alloc(128 * 4);
    float* S1a  = (float*)alloc(HID * 4);
    float* S2a  = (float*)alloc(HID * 4);
    float* S1b  = (float*)alloc(HID * 4);
    float* S2b  = (float*)alloc(HID * 4);
    float* G    = (float*)alloc(128 * HID * 4);
    int*   bsum = (int*)  alloc(2048);
    size_t zbytes = off;
    // ---- fully-overwritten region ----
    int*    flags  = (int*)   alloc(256);
    float*  canon  = (float*) alloc(N_CANON * 4);
    unsigned short* W2T = (unsigned short*)alloc(HID * 256 * 2);
    float*  xf     = (float*) alloc((size_t)N * 4);
    float*  dinv   = (float*) alloc((size_t)N * 4);
    float*  xd1    = (float*) alloc((size_t)N * 4);
    float*  rd     = (float*) alloc((size_t)N * 4);
    float4* node   = (float4*)alloc((size_t)N * 16);
    int*    rowptr = (int*)   alloc((size_t)N * 4);
    int*    col    = (int*)   alloc((size_t)E * 4);
    int*    slot   = (int*)   alloc((size_t)E * 4);
    float*  ab     = (float*) alloc(2 * HID * 4);
    // ---- fast-path buffers (zd + chunked agg), guarded by ws_size ----
    unsigned int* zd = (unsigned int*)alloc((size_t)N * 256);
    size_t availAgg = (ws_size > off) ? (ws_size - off) : 0;
    bool fast = (ws_size >= off) && (availAgg >= (2u << 20));
    unsigned int* agg = (unsigned int*)(ws + off);
    int rowsPer = N, nchunk = 1;
    if (fast) {
        size_t need = (size_t)N * 256;
        if (availAgg < need) {
            rowsPer = (int)(availAgg / 256) & ~31;
            if (rowsPer < 32) fast = false;
            else nchunk = (N + rowsPer - 1) / rowsPer;
        }
    }
    (void)n_in; (void)out_size;

    ConvArgs ca;
    int w_off[14] = { OF_WC1, OF_BC1, OF_WL1, OF_BL1, OF_G1, OF_BE1,
                      OF_WC2, OF_BC2, OF_WL2, OF_BL2, OF_G2, OF_BE2, OF_W3, OF_B3 };
    for (int i = 0; i < 14; i++) { ca.s[i] = w_src[i]; ca.d[i] = canon + w_off[i]; ca.n[i] = w_cnt[i]; }

    const int tb = 256;
    long long zn = (long long)(zbytes / 4);
    k_detect<<<1, 64, 0, stream>>>((const unsigned int*)d_in[7], (const unsigned int*)ei, flags);
    k_zero  <<<(int)((zn + tb - 1) / tb), tb, 0, stream>>>((int*)d_ws, zn);
    k_wconv <<<dim3(64, 14), 256, 0, stream>>>(ca, flags);
    k_wT    <<<(HID * 256 + tb - 1) / tb, tb, 0, stream>>>(canon, W2T);
    k_deg   <<<(E + tb - 1) / tb, tb, 0, stream>>>(ei, E, N, flags, deg, slot);
    k_cnt2  <<<1, 128, 0, stream>>>(bat, N, flags, cnt);
    k_prep  <<<(N + tb - 1) / tb, tb, 0, stream>>>(x, deg, N, flags, dinv, xf, xd1, rd);
    k_scanA <<<NB, 256, 0, stream>>>(deg, N, rowptr, bsum);
    k_scanB <<<1, 512, 0, stream>>>(bsum, NB);
    k_scanC <<<NB, 256, 0, stream>>>(rowptr, bsum, N);
    k_fill  <<<(E + tb - 1) / tb, tb, 0, stream>>>(ei, E, N, flags, rowptr, slot, col, xd1, ps);
    k_node3 <<<(N + tb - 1) / tb, tb, 0, stream>>>(xf, ps, dinv, N, node);
    k_stats1<<<(N + ROWS1 - 1) / ROWS1, HID, 0, stream>>>(node, canon, N, S1a, S2a);
    k_bn1   <<<1, HID, 0, stream>>>(S1a, S2a, canon, N, ab);
    if (fast) {
        k_zmat<<<(N * 64 + tb - 1) / tb, tb, 0, stream>>>(node, canon, ab, N, zd);
        for (int c = 0; c < nchunk; c++) {
            int c0r = c * rowsPer;
            int c1r = min(N, c0r + rowsPer);
            int rows = c1r - c0r;
            k_gather2<<<(rows * 64 + tb - 1) / tb, tb, 0, stream>>>(zd, col, rowptr, deg, dinv,
                                                                    N, E, c0r, c1r, agg);
            k_gemm3<<<(rows + RG - 1) / RG, 128, 0, stream>>>(zd, agg, rd, W2T, canon, bat, flags,
                                                              N, c0r, c1r, S1b, S2b, G);
        }
    } else {
        k_h2f<<<(N + R2 - 1) / R2, HID, 0, stream>>>(node, col, rowptr, deg, ab, canon,
                                                     bat, flags, N, E, S1b, S2b, G);
    }
    k_out<<<128, HID, 0, stream>>>(G, cnt, S1b, S2b, canon, flags, N, d_out);
}